// Round 1
// baseline (811.939 us; speedup 1.0000x reference)
//
#include <hip/hip_runtime.h>

#define N_NODES 50000
#define N_EDGES 1600000
#define N_GRAPHS 256
#define HID 128

// ---------------- CSR build ----------------
__global__ void k_degree(const int* __restrict__ dst, int* __restrict__ cnt) {
    int e = blockIdx.x * blockDim.x + threadIdx.x;
    if (e < N_EDGES) atomicAdd(&cnt[dst[e]], 1);
}

__global__ void k_dis(const int* __restrict__ cnt, float* __restrict__ dis) {
    int n = blockIdx.x * blockDim.x + threadIdx.x;
    if (n < N_NODES) dis[n] = rsqrtf((float)cnt[n] + 1.0f);
}

// single-block exclusive scan of cnt[0..N_NODES) -> offs[0..N_NODES]
__global__ void k_scan(const int* __restrict__ cnt, int* __restrict__ offs) {
    __shared__ int wsum[16];
    __shared__ int srun;
    int t = threadIdx.x;
    int lane = t & 63, w = t >> 6;
    if (t == 0) srun = 0;
    __syncthreads();
    for (int base = 0; base < N_NODES; base += 1024) {
        int i = base + t;
        int v = (i < N_NODES) ? cnt[i] : 0;
        int x = v;
        #pragma unroll
        for (int off = 1; off < 64; off <<= 1) {
            int y = __shfl_up(x, off, 64);
            if (lane >= off) x += y;
        }
        if (lane == 63) wsum[w] = x;
        __syncthreads();
        if (w == 0 && lane < 16) {
            int s = wsum[lane];
            #pragma unroll
            for (int off = 1; off < 16; off <<= 1) {
                int y = __shfl_up(s, off, 64);
                if (lane >= off) s += y;
            }
            wsum[lane] = s;
        }
        __syncthreads();
        int wbase = (w > 0) ? wsum[w - 1] : 0;
        int incl = x + wbase;
        if (i < N_NODES) offs[i] = srun + incl - v;
        __syncthreads();
        if (t == 1023) srun += incl;
        __syncthreads();
    }
    if (t == 0) offs[N_NODES] = srun;
}

__global__ void k_fillcsr(const int* __restrict__ src, const int* __restrict__ dst,
                          const float* __restrict__ dis, const int* __restrict__ offs,
                          int* __restrict__ fill, int* __restrict__ csr_src,
                          float* __restrict__ csr_coef) {
    int e = blockIdx.x * blockDim.x + threadIdx.x;
    if (e >= N_EDGES) return;
    int s = src[e], d = dst[e];
    int p = offs[d] + atomicAdd(&fill[d], 1);
    csr_src[p] = s;
    csr_coef[p] = dis[s] * dis[d];
}

// ---------------- layer math ----------------
// x[N,9] @ W1[9,128] -> out[N,128]
__global__ void k_gemm1(const float* __restrict__ x, const float* __restrict__ W1,
                        float* __restrict__ out) {
    int idx = blockIdx.x * blockDim.x + threadIdx.x;
    if (idx >= N_NODES * HID) return;
    int n = idx >> 7, j = idx & 127;
    const float* xr = x + n * 9;
    float acc = 0.f;
    #pragma unroll
    for (int k = 0; k < 9; k++) acc += xr[k] * W1[k * HID + j];
    out[idx] = acc;
}

// h[N,128] @ W[128,128] -> out[N,128]; 64-node LDS tile, 8-node x float4 reg blocking
__global__ __launch_bounds__(256) void k_gemm128(const float* __restrict__ h,
                                                 const float* __restrict__ W,
                                                 float* __restrict__ out) {
    __shared__ float htile[64 * 128];
    int t = threadIdx.x;
    int n0 = blockIdx.x * 64;
    for (int i = t; i < 64 * 128; i += 256) {
        int n = n0 + (i >> 7);
        htile[i] = (n < N_NODES) ? h[(size_t)n0 * 128 + i] : 0.f;
    }
    __syncthreads();
    int q = t & 31;    // feature quad (j = 4q..4q+3)
    int tn = t >> 5;   // 0..7, each owns 8 rows
    float4 acc[8];
    #pragma unroll
    for (int r = 0; r < 8; r++) acc[r] = make_float4(0.f, 0.f, 0.f, 0.f);
    const float4* W4 = (const float4*)W;
    for (int k = 0; k < 128; k += 2) {
        float4 w0 = W4[k * 32 + q];
        float4 w1 = W4[(k + 1) * 32 + q];
        #pragma unroll
        for (int r = 0; r < 8; r++) {
            int row = tn * 8 + r;
            float2 hk = *(const float2*)&htile[row * 128 + k];
            acc[r].x += hk.x * w0.x; acc[r].y += hk.x * w0.y;
            acc[r].z += hk.x * w0.z; acc[r].w += hk.x * w0.w;
            acc[r].x += hk.y * w1.x; acc[r].y += hk.y * w1.y;
            acc[r].z += hk.y * w1.z; acc[r].w += hk.y * w1.w;
        }
    }
    float4* out4 = (float4*)out;
    #pragma unroll
    for (int r = 0; r < 8; r++) {
        int n = n0 + tn * 8 + r;
        if (n < N_NODES) out4[(size_t)n * 32 + q] = acc[r];
    }
}

// out[n] = sum_e coef[e]*hlin[src[e]] + coef_s[n]*hlin[n] (+bias, relu)
__global__ void k_agg(const float* __restrict__ hlin, const int* __restrict__ offs,
                      const int* __restrict__ csr_src, const float* __restrict__ csr_coef,
                      const float* __restrict__ dis, const float* __restrict__ bias,
                      float* __restrict__ out, int relu) {
    int n = blockIdx.x;
    int f = threadIdx.x;
    int e0 = offs[n], e1 = offs[n + 1];
    float dn = dis[n];
    float acc = hlin[(size_t)n * 128 + f] * (dn * dn);
    int e = e0;
    if (e < e1) {
        int s = csr_src[e];
        float c = csr_coef[e];
        for (++e; e < e1; ++e) {
            int s2 = csr_src[e];
            float c2 = csr_coef[e];
            acc += c * hlin[(size_t)s * 128 + f];
            s = s2; c = c2;
        }
        acc += c * hlin[(size_t)s * 128 + f];
    }
    if (bias) acc += bias[f];
    if (relu) acc = fmaxf(acc, 0.f);
    out[(size_t)n * 128 + f] = acc;
}

// ---------------- pooling ----------------
__global__ void k_count(const int* __restrict__ batch, int* __restrict__ counts) {
    int n = blockIdx.x * blockDim.x + threadIdx.x;
    if (n < N_NODES) atomicAdd(&counts[batch[n]], 1);
}

// 16 nodes per block, run-length accumulate (batch is sorted) then atomic flush
__global__ void k_pool(const float* __restrict__ X, const int* __restrict__ batch,
                       float* __restrict__ sums) {
    int f = threadIdx.x;
    int n0 = blockIdx.x * 16;
    int gprev = -1;
    float acc = 0.f;
    for (int i = 0; i < 16; i++) {
        int n = n0 + i;
        if (n >= N_NODES) break;
        int g = batch[n];
        float v = X[(size_t)n * 128 + f];
        if (g != gprev) {
            if (gprev >= 0) atomicAdd(&sums[gprev * 128 + f], acc);
            acc = 0.f;
            gprev = g;
        }
        acc += v;
    }
    if (gprev >= 0) atomicAdd(&sums[gprev * 128 + f], acc);
}

// out[g] = (sums[g]/max(cnt,1)) @ W3 + b3
__global__ void k_final(const float* __restrict__ sums, const int* __restrict__ counts,
                        const float* __restrict__ W3, const float* __restrict__ b3,
                        float* __restrict__ out) {
    int idx = blockIdx.x * blockDim.x + threadIdx.x;
    if (idx >= N_GRAPHS * HID) return;
    int g = idx >> 7, j = idx & 127;
    float inv = 1.0f / fmaxf((float)counts[g], 1.0f);
    const float* srow = sums + g * 128;
    float acc = 0.f;
    for (int k = 0; k < 128; k++) acc += srow[k] * W3[k * 128 + j];
    out[idx] = acc * inv + b3[j];
}

extern "C" void kernel_launch(void* const* d_in, const int* in_sizes, int n_in,
                              void* d_out, int out_size, void* d_ws, size_t ws_size,
                              hipStream_t stream) {
    const float* x     = (const float*)d_in[0];
    const int*   ei    = (const int*)d_in[1];
    const int*   batch = (const int*)d_in[2];
    const float* W1    = (const float*)d_in[3];
    const float* b1    = (const float*)d_in[4];
    const float* W2    = (const float*)d_in[5];
    const float* b2    = (const float*)d_in[6];
    const float* W3    = (const float*)d_in[7];
    const float* b3    = (const float*)d_in[8];
    float* out = (float*)d_out;
    const int* src = ei;
    const int* dst = ei + N_EDGES;

    char* ws = (char*)d_ws;
    size_t off = 0;
    auto alloc = [&](size_t bytes) -> void* {
        void* p = ws + off;
        off += (bytes + 255) & ~(size_t)255;
        return p;
    };
    float* bufA     = (float*)alloc((size_t)N_NODES * 128 * 4);
    float* bufB     = (float*)alloc((size_t)N_NODES * 128 * 4);
    int*   csr_src  = (int*)alloc((size_t)N_EDGES * 4);
    float* csr_coef = (float*)alloc((size_t)N_EDGES * 4);
    int*   cnt      = (int*)alloc((size_t)N_NODES * 4);
    int*   offs     = (int*)alloc((size_t)(N_NODES + 1) * 4);
    int*   fill     = (int*)alloc((size_t)N_NODES * 4);
    float* dis      = (float*)alloc((size_t)N_NODES * 4);
    float* sums     = (float*)alloc((size_t)N_GRAPHS * 128 * 4);
    int*   counts   = (int*)alloc((size_t)N_GRAPHS * 4);

    hipMemsetAsync(cnt, 0, (size_t)N_NODES * 4, stream);
    hipMemsetAsync(fill, 0, (size_t)N_NODES * 4, stream);
    hipMemsetAsync(sums, 0, (size_t)N_GRAPHS * 128 * 4, stream);
    hipMemsetAsync(counts, 0, (size_t)N_GRAPHS * 4, stream);

    k_degree<<<(N_EDGES + 255) / 256, 256, 0, stream>>>(dst, cnt);
    k_dis<<<(N_NODES + 255) / 256, 256, 0, stream>>>(cnt, dis);
    k_scan<<<1, 1024, 0, stream>>>(cnt, offs);
    k_fillcsr<<<(N_EDGES + 255) / 256, 256, 0, stream>>>(src, dst, dis, offs, fill,
                                                         csr_src, csr_coef);
    k_count<<<(N_NODES + 255) / 256, 256, 0, stream>>>(batch, counts);

    // layer 1: h1 = relu(agg(x@W1) + b1)
    k_gemm1<<<(N_NODES * HID + 255) / 256, 256, 0, stream>>>(x, W1, bufA);
    k_agg<<<N_NODES, 128, 0, stream>>>(bufA, offs, csr_src, csr_coef, dis, b1, bufB, 1);
    // layer 2: h2 = relu(agg(h1@W2) + b2)
    k_gemm128<<<(N_NODES + 63) / 64, 256, 0, stream>>>(bufB, W2, bufA);
    k_agg<<<N_NODES, 128, 0, stream>>>(bufA, offs, csr_src, csr_coef, dis, b2, bufB, 1);
    // layer 3 (W3 deferred past pooling): X = agg(h2) + coef_s*h2
    k_agg<<<N_NODES, 128, 0, stream>>>(bufB, offs, csr_src, csr_coef, dis, nullptr, bufA, 0);
    // pool + final tiny GEMM
    k_pool<<<(N_NODES + 15) / 16, 128, 0, stream>>>(bufA, batch, sums);
    k_final<<<(N_GRAPHS * HID + 255) / 256, 256, 0, stream>>>(sums, counts, W3, b3, out);
}

// Round 2
// 579.354 us; speedup vs baseline: 1.4015x; 1.4015x over previous
//
#include <hip/hip_runtime.h>

#define N_NODES 50000
#define N_EDGES 1600000
#define N_GRAPHS 256
#define HID 128

// ---------------- CSR build ----------------
__global__ void k_degree(const int* __restrict__ dst, int* __restrict__ cnt) {
    int e = blockIdx.x * blockDim.x + threadIdx.x;
    if (e < N_EDGES) atomicAdd(&cnt[dst[e]], 1);
}

__global__ void k_dis(const int* __restrict__ cnt, float* __restrict__ dis) {
    int n = blockIdx.x * blockDim.x + threadIdx.x;
    if (n < N_NODES) dis[n] = rsqrtf((float)cnt[n] + 1.0f);
}

// single-block exclusive scan of cnt[0..N_NODES) -> offs[0..N_NODES]
__global__ void k_scan(const int* __restrict__ cnt, int* __restrict__ offs) {
    __shared__ int wsum[16];
    __shared__ int srun;
    int t = threadIdx.x;
    int lane = t & 63, w = t >> 6;
    if (t == 0) srun = 0;
    __syncthreads();
    for (int base = 0; base < N_NODES; base += 1024) {
        int i = base + t;
        int v = (i < N_NODES) ? cnt[i] : 0;
        int x = v;
        #pragma unroll
        for (int off = 1; off < 64; off <<= 1) {
            int y = __shfl_up(x, off, 64);
            if (lane >= off) x += y;
        }
        if (lane == 63) wsum[w] = x;
        __syncthreads();
        if (w == 0 && lane < 16) {
            int s = wsum[lane];
            #pragma unroll
            for (int off = 1; off < 16; off <<= 1) {
                int y = __shfl_up(s, off, 64);
                if (lane >= off) s += y;
            }
            wsum[lane] = s;
        }
        __syncthreads();
        int wbase = (w > 0) ? wsum[w - 1] : 0;
        int incl = x + wbase;
        if (i < N_NODES) offs[i] = srun + incl - v;
        __syncthreads();
        if (t == 1023) srun += incl;
        __syncthreads();
    }
    if (t == 0) offs[N_NODES] = srun;
}

__global__ void k_fillcsr(const int* __restrict__ src, const int* __restrict__ dst,
                          const float* __restrict__ dis, const int* __restrict__ offs,
                          int* __restrict__ fill, int* __restrict__ csr_src,
                          float* __restrict__ csr_coef) {
    int e = blockIdx.x * blockDim.x + threadIdx.x;
    if (e >= N_EDGES) return;
    int s = src[e], d = dst[e];
    int p = offs[d] + atomicAdd(&fill[d], 1);
    csr_src[p] = s;
    csr_coef[p] = dis[s] * dis[d];
}

// ---------------- layer 1 in 9-dim space ----------------
// pad x[N,9] -> x16[N,16] (one 64B line per row)
__global__ void k_pad(const float* __restrict__ x, float* __restrict__ x16) {
    int idx = blockIdx.x * blockDim.x + threadIdx.x;
    if (idx >= N_NODES * 16) return;
    int n = idx >> 4, f = idx & 15;
    x16[idx] = (f < 9) ? x[n * 9 + f] : 0.f;
}

// y[n] = sum_e coef*x16[src] + coef_s*x16[n]  -- wave per node, 4 edge-slots x 16 lanes
__global__ __launch_bounds__(256) void k_agg9(const float* __restrict__ x16,
                                              const int* __restrict__ offs,
                                              const int* __restrict__ csr_src,
                                              const float* __restrict__ csr_coef,
                                              const float* __restrict__ dis,
                                              float* __restrict__ y) {
    int wv = threadIdx.x >> 6, lane = threadIdx.x & 63;
    int n = blockIdx.x * 4 + wv;
    if (n >= N_NODES) return;
    int slot = lane >> 4, fl = lane & 15;
    int e0 = offs[n], e1 = offs[n + 1];
    float acc = 0.f;
    for (int e = e0 + slot; e < e1; e += 16) {
        int ss[4]; float cc[4];
        #pragma unroll
        for (int i = 0; i < 4; i++) {
            int ei = e + i * 4;
            bool ok = ei < e1;
            ss[i] = ok ? csr_src[ei] : n;
            cc[i] = ok ? csr_coef[ei] : 0.f;
        }
        #pragma unroll
        for (int i = 0; i < 4; i++)
            acc += cc[i] * x16[(size_t)ss[i] * 16 + fl];
    }
    acc += __shfl_xor(acc, 16, 64);
    acc += __shfl_xor(acc, 32, 64);
    float dn = dis[n];
    acc += dn * dn * x16[(size_t)n * 16 + fl];
    if (slot == 0) y[(size_t)n * 16 + fl] = acc;
}

// h1 = relu(y @ W1 + b1)   y:[N,16] (9 used), W1:[9,128]
__global__ void k_gemm1(const float* __restrict__ y16, const float* __restrict__ W1,
                        const float* __restrict__ b1, float* __restrict__ out) {
    int idx = blockIdx.x * blockDim.x + threadIdx.x;
    if (idx >= N_NODES * HID) return;
    int n = idx >> 7, j = idx & 127;
    const float* yr = y16 + (size_t)n * 16;
    float acc = b1[j];
    #pragma unroll
    for (int k = 0; k < 9; k++) acc += yr[k] * W1[k * HID + j];
    out[idx] = fmaxf(acc, 0.f);
}

// ---------------- 128-dim layers ----------------
// h[N,128] @ W[128,128] -> out[N,128]; 64-node LDS tile, 8-node x float4 reg blocking
__global__ __launch_bounds__(256) void k_gemm128(const float* __restrict__ h,
                                                 const float* __restrict__ W,
                                                 float* __restrict__ out) {
    __shared__ float htile[64 * 128];
    int t = threadIdx.x;
    int n0 = blockIdx.x * 64;
    for (int i = t; i < 64 * 128; i += 256) {
        int n = n0 + (i >> 7);
        htile[i] = (n < N_NODES) ? h[(size_t)n0 * 128 + i] : 0.f;
    }
    __syncthreads();
    int q = t & 31;
    int tn = t >> 5;
    float4 acc[8];
    #pragma unroll
    for (int r = 0; r < 8; r++) acc[r] = make_float4(0.f, 0.f, 0.f, 0.f);
    const float4* W4 = (const float4*)W;
    for (int k = 0; k < 128; k += 2) {
        float4 w0 = W4[k * 32 + q];
        float4 w1 = W4[(k + 1) * 32 + q];
        #pragma unroll
        for (int r = 0; r < 8; r++) {
            int row = tn * 8 + r;
            float2 hk = *(const float2*)&htile[row * 128 + k];
            acc[r].x += hk.x * w0.x; acc[r].y += hk.x * w0.y;
            acc[r].z += hk.x * w0.z; acc[r].w += hk.x * w0.w;
            acc[r].x += hk.y * w1.x; acc[r].y += hk.y * w1.y;
            acc[r].z += hk.y * w1.z; acc[r].w += hk.y * w1.w;
        }
    }
    float4* out4 = (float4*)out;
    #pragma unroll
    for (int r = 0; r < 8; r++) {
        int n = n0 + tn * 8 + r;
        if (n < N_NODES) out4[(size_t)n * 32 + q] = acc[r];
    }
}

// wave-per-node gather-agg, float2 per lane, 8-edge software pipeline
__global__ __launch_bounds__(256) void k_agg(const float* __restrict__ hlin,
                                             const int* __restrict__ offs,
                                             const int* __restrict__ csr_src,
                                             const float* __restrict__ csr_coef,
                                             const float* __restrict__ dis,
                                             const float* __restrict__ bias,
                                             float* __restrict__ out, int relu) {
    int wv = threadIdx.x >> 6, lane = threadIdx.x & 63;
    int n = blockIdx.x * 4 + wv;
    if (n >= N_NODES) return;
    int e0 = offs[n], e1 = offs[n + 1];
    float dn = dis[n];
    float2 hv = *(const float2*)&hlin[(size_t)n * 128 + lane * 2];
    float2 acc;
    acc.x = hv.x * dn * dn;
    acc.y = hv.y * dn * dn;
    for (int e = e0; e < e1; e += 8) {
        int ss[8]; float cc[8];
        #pragma unroll
        for (int i = 0; i < 8; i++) {
            int ei = e + i;
            bool ok = ei < e1;
            ss[i] = ok ? csr_src[ei] : n;
            cc[i] = ok ? csr_coef[ei] : 0.f;
        }
        float2 rows[8];
        #pragma unroll
        for (int i = 0; i < 8; i++)
            rows[i] = *(const float2*)&hlin[(size_t)ss[i] * 128 + lane * 2];
        #pragma unroll
        for (int i = 0; i < 8; i++) {
            acc.x += cc[i] * rows[i].x;
            acc.y += cc[i] * rows[i].y;
        }
    }
    if (bias) {
        float2 bb = *(const float2*)&bias[lane * 2];
        acc.x += bb.x; acc.y += bb.y;
    }
    if (relu) {
        acc.x = fmaxf(acc.x, 0.f);
        acc.y = fmaxf(acc.y, 0.f);
    }
    *(float2*)&out[(size_t)n * 128 + lane * 2] = acc;
}

// ---------------- pooling ----------------
__global__ void k_count(const int* __restrict__ batch, int* __restrict__ counts) {
    int n = blockIdx.x * blockDim.x + threadIdx.x;
    if (n < N_NODES) atomicAdd(&counts[batch[n]], 1);
}

__global__ void k_pool(const float* __restrict__ X, const int* __restrict__ batch,
                       float* __restrict__ sums) {
    int f = threadIdx.x;
    int n0 = blockIdx.x * 16;
    int gprev = -1;
    float acc = 0.f;
    for (int i = 0; i < 16; i++) {
        int n = n0 + i;
        if (n >= N_NODES) break;
        int g = batch[n];
        float v = X[(size_t)n * 128 + f];
        if (g != gprev) {
            if (gprev >= 0) atomicAdd(&sums[gprev * 128 + f], acc);
            acc = 0.f;
            gprev = g;
        }
        acc += v;
    }
    if (gprev >= 0) atomicAdd(&sums[gprev * 128 + f], acc);
}

__global__ void k_final(const float* __restrict__ sums, const int* __restrict__ counts,
                        const float* __restrict__ W3, const float* __restrict__ b3,
                        float* __restrict__ out) {
    int idx = blockIdx.x * blockDim.x + threadIdx.x;
    if (idx >= N_GRAPHS * HID) return;
    int g = idx >> 7, j = idx & 127;
    float inv = 1.0f / fmaxf((float)counts[g], 1.0f);
    const float* srow = sums + g * 128;
    float acc = 0.f;
    for (int k = 0; k < 128; k++) acc += srow[k] * W3[k * 128 + j];
    out[idx] = acc * inv + b3[j];
}

extern "C" void kernel_launch(void* const* d_in, const int* in_sizes, int n_in,
                              void* d_out, int out_size, void* d_ws, size_t ws_size,
                              hipStream_t stream) {
    const float* x     = (const float*)d_in[0];
    const int*   ei    = (const int*)d_in[1];
    const int*   batch = (const int*)d_in[2];
    const float* W1    = (const float*)d_in[3];
    const float* b1    = (const float*)d_in[4];
    const float* W2    = (const float*)d_in[5];
    const float* b2    = (const float*)d_in[6];
    const float* W3    = (const float*)d_in[7];
    const float* b3    = (const float*)d_in[8];
    float* out = (float*)d_out;
    const int* src = ei;
    const int* dst = ei + N_EDGES;

    char* ws = (char*)d_ws;
    size_t off = 0;
    auto alloc = [&](size_t bytes) -> void* {
        void* p = ws + off;
        off += (bytes + 255) & ~(size_t)255;
        return p;
    };
    float* bufA     = (float*)alloc((size_t)N_NODES * 128 * 4);
    float* bufB     = (float*)alloc((size_t)N_NODES * 128 * 4);
    int*   csr_src  = (int*)alloc((size_t)N_EDGES * 4);
    float* csr_coef = (float*)alloc((size_t)N_EDGES * 4);
    int*   cnt      = (int*)alloc((size_t)N_NODES * 4);
    int*   offs     = (int*)alloc((size_t)(N_NODES + 1) * 4);
    int*   fill     = (int*)alloc((size_t)N_NODES * 4);
    float* dis      = (float*)alloc((size_t)N_NODES * 4);
    float* sums     = (float*)alloc((size_t)N_GRAPHS * 128 * 4);
    int*   counts   = (int*)alloc((size_t)N_GRAPHS * 4);
    float* x16      = (float*)alloc((size_t)N_NODES * 16 * 4);
    float* y16      = (float*)alloc((size_t)N_NODES * 16 * 4);

    hipMemsetAsync(cnt, 0, (size_t)N_NODES * 4, stream);
    hipMemsetAsync(fill, 0, (size_t)N_NODES * 4, stream);
    hipMemsetAsync(sums, 0, (size_t)N_GRAPHS * 128 * 4, stream);
    hipMemsetAsync(counts, 0, (size_t)N_GRAPHS * 4, stream);

    k_degree<<<(N_EDGES + 255) / 256, 256, 0, stream>>>(dst, cnt);
    k_dis<<<(N_NODES + 255) / 256, 256, 0, stream>>>(cnt, dis);
    k_scan<<<1, 1024, 0, stream>>>(cnt, offs);
    k_fillcsr<<<(N_EDGES + 255) / 256, 256, 0, stream>>>(src, dst, dis, offs, fill,
                                                         csr_src, csr_coef);
    k_count<<<(N_NODES + 255) / 256, 256, 0, stream>>>(batch, counts);
    k_pad<<<(N_NODES * 16 + 255) / 256, 256, 0, stream>>>(x, x16);

    // layer 1: aggregate in 9-dim space, then h1 = relu(y @ W1 + b1)
    k_agg9<<<(N_NODES + 3) / 4, 256, 0, stream>>>(x16, offs, csr_src, csr_coef, dis, y16);
    k_gemm1<<<(N_NODES * HID + 255) / 256, 256, 0, stream>>>(y16, W1, b1, bufB);
    // layer 2: h2 = relu(agg(h1@W2) + b2)
    k_gemm128<<<(N_NODES + 63) / 64, 256, 0, stream>>>(bufB, W2, bufA);
    k_agg<<<(N_NODES + 3) / 4, 256, 0, stream>>>(bufA, offs, csr_src, csr_coef, dis, b2, bufB, 1);
    // layer 3 (W3 deferred past pooling): X = agg(h2) + coef_s*h2
    k_agg<<<(N_NODES + 3) / 4, 256, 0, stream>>>(bufB, offs, csr_src, csr_coef, dis, nullptr, bufA, 0);
    // pool + final tiny GEMM
    k_pool<<<(N_NODES + 15) / 16, 128, 0, stream>>>(bufA, batch, sums);
    k_final<<<(N_GRAPHS * HID + 255) / 256, 256, 0, stream>>>(sums, counts, W3, b3, out);
}

// Round 3
// 565.741 us; speedup vs baseline: 1.4352x; 1.0241x over previous
//
#include <hip/hip_runtime.h>

#define N_NODES 50000
#define N_EDGES 1600000
#define N_GRAPHS 256
#define HID 128

// ---------------- block scan helper (256 threads, 4 waves) ----------------
__device__ __forceinline__ int block_excl_scan256(int v, int t) {
    __shared__ int ws[4];
    int lane = t & 63, w = t >> 6;
    int x = v;
    #pragma unroll
    for (int off = 1; off < 64; off <<= 1) {
        int y = __shfl_up(x, off, 64);
        if (lane >= off) x += y;
    }
    if (lane == 63) ws[w] = x;
    __syncthreads();
    int b0 = ws[0], b1 = ws[1], b2 = ws[2];
    int wbase = (w > 0 ? b0 : 0) + (w > 1 ? b1 : 0) + (w > 2 ? b2 : 0);
    return wbase + x - v;  // exclusive
}

// ---------------- CSR build ----------------
__global__ void k_degree(const int* __restrict__ dst, int* __restrict__ cnt) {
    int i = (blockIdx.x * blockDim.x + threadIdx.x) * 4;
    if (i + 3 < N_EDGES) {
        int4 d = *(const int4*)&dst[i];
        atomicAdd(&cnt[d.x], 1);
        atomicAdd(&cnt[d.y], 1);
        atomicAdd(&cnt[d.z], 1);
        atomicAdd(&cnt[d.w], 1);
    } else {
        for (int e = i; e < N_EDGES; e++) atomicAdd(&cnt[dst[e]], 1);
    }
}

#define SCAN_NB ((N_NODES + 255) / 256)  // 196

__global__ void k_scan_part(const int* __restrict__ cnt, int* __restrict__ part) {
    __shared__ int ws[4];
    int t = threadIdx.x;
    int i = blockIdx.x * 256 + t;
    int v = (i < N_NODES) ? cnt[i] : 0;
    int lane = t & 63, w = t >> 6;
    #pragma unroll
    for (int off = 1; off < 64; off <<= 1) v += __shfl_xor(v, off, 64);
    if (lane == 0) ws[w] = v;
    __syncthreads();
    if (t == 0) part[blockIdx.x] = ws[0] + ws[1] + ws[2] + ws[3];
}

__global__ void k_scan_mid(int* __restrict__ part, int* __restrict__ offs) {
    int t = threadIdx.x;
    int v = (t < SCAN_NB) ? part[t] : 0;
    int ex = block_excl_scan256(v, t);
    if (t < SCAN_NB) part[t] = ex;
    if (t == 255) offs[N_NODES] = ex + v;  // v==0 here, ex == grand total
}

__global__ void k_scan_add(const int* __restrict__ cnt, const int* __restrict__ part,
                           int* __restrict__ offs, int* __restrict__ offs2,
                           float* __restrict__ dis) {
    int t = threadIdx.x;
    int i = blockIdx.x * 256 + t;
    int v = (i < N_NODES) ? cnt[i] : 0;
    int ex = block_excl_scan256(v, t);
    if (i < N_NODES) {
        int o = part[blockIdx.x] + ex;
        offs[i] = o;
        offs2[i] = o;
        dis[i] = rsqrtf((float)v + 1.0f);
    }
}

__global__ void k_fillcsr(const int* __restrict__ src, const int* __restrict__ dst,
                          const float* __restrict__ dis, int* __restrict__ offs2,
                          int* __restrict__ csr_src, float* __restrict__ csr_coef) {
    int e = blockIdx.x * blockDim.x + threadIdx.x;
    if (e >= N_EDGES) return;
    int s = src[e], d = dst[e];
    int p = atomicAdd(&offs2[d], 1);
    csr_src[p] = s;
    csr_coef[p] = dis[s] * dis[d];
}

// ---------------- layer 1 in 9-dim space ----------------
// pad x[N,9] -> x16[N,16]; fold batch counting in (f==0 lane)
__global__ void k_pad(const float* __restrict__ x, float* __restrict__ x16,
                      const int* __restrict__ batch, int* __restrict__ counts) {
    int idx = blockIdx.x * blockDim.x + threadIdx.x;
    if (idx >= N_NODES * 16) return;
    int n = idx >> 4, f = idx & 15;
    x16[idx] = (f < 9) ? x[n * 9 + f] : 0.f;
    if (f == 0) atomicAdd(&counts[batch[n]], 1);
}

// y[n] = sum_e coef*x16[src] + coef_s*x16[n]  -- wave per node, 4 edge-slots x 16 lanes
__global__ __launch_bounds__(256) void k_agg9(const float* __restrict__ x16,
                                              const int* __restrict__ offs,
                                              const int* __restrict__ csr_src,
                                              const float* __restrict__ csr_coef,
                                              const float* __restrict__ dis,
                                              float* __restrict__ y) {
    int wv = threadIdx.x >> 6, lane = threadIdx.x & 63;
    int n = blockIdx.x * 4 + wv;
    if (n >= N_NODES) return;
    int slot = lane >> 4, fl = lane & 15;
    int e0 = offs[n], e1 = offs[n + 1];
    float acc = 0.f;
    for (int e = e0 + slot; e < e1; e += 16) {
        int ss[4]; float cc[4];
        #pragma unroll
        for (int i = 0; i < 4; i++) {
            int ei = e + i * 4;
            bool ok = ei < e1;
            ss[i] = ok ? csr_src[ei] : n;
            cc[i] = ok ? csr_coef[ei] : 0.f;
        }
        #pragma unroll
        for (int i = 0; i < 4; i++)
            acc += cc[i] * x16[(size_t)ss[i] * 16 + fl];
    }
    acc += __shfl_xor(acc, 16, 64);
    acc += __shfl_xor(acc, 32, 64);
    float dn = dis[n];
    acc += dn * dn * x16[(size_t)n * 16 + fl];
    if (slot == 0) y[(size_t)n * 16 + fl] = acc;
}

// h1 = relu(y @ W1 + b1)   y:[N,16] (9 used), W1:[9,128]
__global__ void k_gemm1(const float* __restrict__ y16, const float* __restrict__ W1,
                        const float* __restrict__ b1, float* __restrict__ out) {
    int idx = blockIdx.x * blockDim.x + threadIdx.x;
    if (idx >= N_NODES * HID) return;
    int n = idx >> 7, j = idx & 127;
    const float* yr = y16 + (size_t)n * 16;
    float acc = b1[j];
    #pragma unroll
    for (int k = 0; k < 9; k++) acc += yr[k] * W1[k * HID + j];
    out[idx] = fmaxf(acc, 0.f);
}

// ---------------- 128-dim layers ----------------
__global__ __launch_bounds__(256) void k_gemm128(const float* __restrict__ h,
                                                 const float* __restrict__ W,
                                                 float* __restrict__ out) {
    __shared__ float htile[64 * 128];
    int t = threadIdx.x;
    int n0 = blockIdx.x * 64;
    for (int i = t; i < 64 * 128; i += 256) {
        int n = n0 + (i >> 7);
        htile[i] = (n < N_NODES) ? h[(size_t)n0 * 128 + i] : 0.f;
    }
    __syncthreads();
    int q = t & 31;
    int tn = t >> 5;
    float4 acc[8];
    #pragma unroll
    for (int r = 0; r < 8; r++) acc[r] = make_float4(0.f, 0.f, 0.f, 0.f);
    const float4* W4 = (const float4*)W;
    for (int k = 0; k < 128; k += 2) {
        float4 w0 = W4[k * 32 + q];
        float4 w1 = W4[(k + 1) * 32 + q];
        #pragma unroll
        for (int r = 0; r < 8; r++) {
            int row = tn * 8 + r;
            float2 hk = *(const float2*)&htile[row * 128 + k];
            acc[r].x += hk.x * w0.x; acc[r].y += hk.x * w0.y;
            acc[r].z += hk.x * w0.z; acc[r].w += hk.x * w0.w;
            acc[r].x += hk.y * w1.x; acc[r].y += hk.y * w1.y;
            acc[r].z += hk.y * w1.z; acc[r].w += hk.y * w1.w;
        }
    }
    float4* out4 = (float4*)out;
    #pragma unroll
    for (int r = 0; r < 8; r++) {
        int n = n0 + tn * 8 + r;
        if (n < N_NODES) out4[(size_t)n * 32 + q] = acc[r];
    }
}

// wave-per-node gather-agg: lane = float4, 32 lanes/row, 2 edges per load instr,
// 16 edges in flight
__global__ __launch_bounds__(256) void k_agg(const float* __restrict__ hlin,
                                             const int* __restrict__ offs,
                                             const int* __restrict__ csr_src,
                                             const float* __restrict__ csr_coef,
                                             const float* __restrict__ dis,
                                             const float* __restrict__ bias,
                                             float* __restrict__ out, int relu) {
    int wv = threadIdx.x >> 6, lane = threadIdx.x & 63;
    int n = blockIdx.x * 4 + wv;
    if (n >= N_NODES) return;
    int half = lane >> 5;   // which edge of the pair
    int fl = lane & 31;     // feature quad: features 4*fl..4*fl+3
    int e0 = offs[n], e1 = offs[n + 1];
    const float4* h4 = (const float4*)hlin;
    float4 acc = make_float4(0.f, 0.f, 0.f, 0.f);
    for (int e = e0 + half; e < e1; e += 16) {
        int ss[8]; float cc[8];
        #pragma unroll
        for (int i = 0; i < 8; i++) {
            int ei = e + i * 2;
            bool ok = ei < e1;
            ss[i] = ok ? csr_src[ei] : n;
            cc[i] = ok ? csr_coef[ei] : 0.f;
        }
        float4 rows[8];
        #pragma unroll
        for (int i = 0; i < 8; i++)
            rows[i] = h4[(size_t)ss[i] * 32 + fl];
        #pragma unroll
        for (int i = 0; i < 8; i++) {
            acc.x += cc[i] * rows[i].x;
            acc.y += cc[i] * rows[i].y;
            acc.z += cc[i] * rows[i].z;
            acc.w += cc[i] * rows[i].w;
        }
    }
    // combine the two edge-halves
    acc.x += __shfl_xor(acc.x, 32, 64);
    acc.y += __shfl_xor(acc.y, 32, 64);
    acc.z += __shfl_xor(acc.z, 32, 64);
    acc.w += __shfl_xor(acc.w, 32, 64);
    // self loop + bias + relu
    float dn = dis[n];
    float4 hv = h4[(size_t)n * 32 + fl];
    acc.x += dn * dn * hv.x;
    acc.y += dn * dn * hv.y;
    acc.z += dn * dn * hv.z;
    acc.w += dn * dn * hv.w;
    if (bias) {
        float4 bb = ((const float4*)bias)[fl];
        acc.x += bb.x; acc.y += bb.y; acc.z += bb.z; acc.w += bb.w;
    }
    if (relu) {
        acc.x = fmaxf(acc.x, 0.f);
        acc.y = fmaxf(acc.y, 0.f);
        acc.z = fmaxf(acc.z, 0.f);
        acc.w = fmaxf(acc.w, 0.f);
    }
    if (half == 0) ((float4*)out)[(size_t)n * 32 + fl] = acc;
}

// ---------------- pooling ----------------
__global__ void k_pool(const float* __restrict__ X, const int* __restrict__ batch,
                       float* __restrict__ sums) {
    int f = threadIdx.x;
    int n0 = blockIdx.x * 16;
    int gprev = -1;
    float acc = 0.f;
    for (int i = 0; i < 16; i++) {
        int n = n0 + i;
        if (n >= N_NODES) break;
        int g = batch[n];
        float v = X[(size_t)n * 128 + f];
        if (g != gprev) {
            if (gprev >= 0) atomicAdd(&sums[gprev * 128 + f], acc);
            acc = 0.f;
            gprev = g;
        }
        acc += v;
    }
    if (gprev >= 0) atomicAdd(&sums[gprev * 128 + f], acc);
}

__global__ void k_final(const float* __restrict__ sums, const int* __restrict__ counts,
                        const float* __restrict__ W3, const float* __restrict__ b3,
                        float* __restrict__ out) {
    int idx = blockIdx.x * blockDim.x + threadIdx.x;
    if (idx >= N_GRAPHS * HID) return;
    int g = idx >> 7, j = idx & 127;
    float inv = 1.0f / fmaxf((float)counts[g], 1.0f);
    const float* srow = sums + g * 128;
    float acc = 0.f;
    for (int k = 0; k < 128; k++) acc += srow[k] * W3[k * 128 + j];
    out[idx] = acc * inv + b3[j];
}

extern "C" void kernel_launch(void* const* d_in, const int* in_sizes, int n_in,
                              void* d_out, int out_size, void* d_ws, size_t ws_size,
                              hipStream_t stream) {
    const float* x     = (const float*)d_in[0];
    const int*   ei    = (const int*)d_in[1];
    const int*   batch = (const int*)d_in[2];
    const float* W1    = (const float*)d_in[3];
    const float* b1    = (const float*)d_in[4];
    const float* W2    = (const float*)d_in[5];
    const float* b2    = (const float*)d_in[6];
    const float* W3    = (const float*)d_in[7];
    const float* b3    = (const float*)d_in[8];
    float* out = (float*)d_out;
    const int* src = ei;
    const int* dst = ei + N_EDGES;

    char* ws = (char*)d_ws;
    size_t off = 0;
    auto alloc = [&](size_t bytes) -> void* {
        void* p = ws + off;
        off += (bytes + 255) & ~(size_t)255;
        return p;
    };
    float* bufA     = (float*)alloc((size_t)N_NODES * 128 * 4);
    float* bufB     = (float*)alloc((size_t)N_NODES * 128 * 4);
    int*   csr_src  = (int*)alloc((size_t)N_EDGES * 4);
    float* csr_coef = (float*)alloc((size_t)N_EDGES * 4);
    int*   cnt      = (int*)alloc((size_t)N_NODES * 4);
    int*   offs     = (int*)alloc((size_t)(N_NODES + 1) * 4);
    int*   offs2    = (int*)alloc((size_t)N_NODES * 4);
    float* dis      = (float*)alloc((size_t)N_NODES * 4);
    float* sums     = (float*)alloc((size_t)N_GRAPHS * 128 * 4);
    int*   counts   = (int*)alloc((size_t)N_GRAPHS * 4);
    float* x16      = (float*)alloc((size_t)N_NODES * 16 * 4);
    float* y16      = (float*)alloc((size_t)N_NODES * 16 * 4);
    int*   part     = (int*)alloc((size_t)SCAN_NB * 4);

    hipMemsetAsync(cnt, 0, (size_t)N_NODES * 4, stream);
    hipMemsetAsync(sums, 0, (size_t)N_GRAPHS * 128 * 4, stream);
    hipMemsetAsync(counts, 0, (size_t)N_GRAPHS * 4, stream);

    k_degree<<<(N_EDGES / 4 + 255) / 256, 256, 0, stream>>>(dst, cnt);
    k_scan_part<<<SCAN_NB, 256, 0, stream>>>(cnt, part);
    k_scan_mid<<<1, 256, 0, stream>>>(part, offs);
    k_scan_add<<<SCAN_NB, 256, 0, stream>>>(cnt, part, offs, offs2, dis);
    k_fillcsr<<<(N_EDGES + 255) / 256, 256, 0, stream>>>(src, dst, dis, offs2,
                                                         csr_src, csr_coef);
    k_pad<<<(N_NODES * 16 + 255) / 256, 256, 0, stream>>>(x, x16, batch, counts);

    // layer 1: aggregate in 9-dim space, then h1 = relu(y @ W1 + b1)
    k_agg9<<<(N_NODES + 3) / 4, 256, 0, stream>>>(x16, offs, csr_src, csr_coef, dis, y16);
    k_gemm1<<<(N_NODES * HID + 255) / 256, 256, 0, stream>>>(y16, W1, b1, bufB);
    // layer 2: h2 = relu(agg(h1@W2) + b2)
    k_gemm128<<<(N_NODES + 63) / 64, 256, 0, stream>>>(bufB, W2, bufA);
    k_agg<<<(N_NODES + 3) / 4, 256, 0, stream>>>(bufA, offs, csr_src, csr_coef, dis, b2, bufB, 1);
    // layer 3 (W3 deferred past pooling): X = agg(h2) + coef_s*h2
    k_agg<<<(N_NODES + 3) / 4, 256, 0, stream>>>(bufB, offs, csr_src, csr_coef, dis, nullptr, bufA, 0);
    // pool + final tiny GEMM
    k_pool<<<(N_NODES + 15) / 16, 128, 0, stream>>>(bufA, batch, sums);
    k_final<<<(N_GRAPHS * HID + 255) / 256, 256, 0, stream>>>(sums, counts, W3, b3, out);
}

// Round 4
// 490.666 us; speedup vs baseline: 1.6548x; 1.1530x over previous
//
#include <hip/hip_runtime.h>

#define N_NODES 50000
#define N_EDGES 1600000
#define N_GRAPHS 256
#define HID 128

// ---------------- bf16 helpers ----------------
__device__ __forceinline__ float4 bf4_to_f4(uint2 v) {
    float4 r;
    r.x = __uint_as_float(v.x << 16);
    r.y = __uint_as_float(v.x & 0xffff0000u);
    r.z = __uint_as_float(v.y << 16);
    r.w = __uint_as_float(v.y & 0xffff0000u);
    return r;
}
__device__ __forceinline__ unsigned f2bf(float f) {
    unsigned u = __float_as_uint(f);
    return (u + 0x7fffu + ((u >> 16) & 1u)) >> 16;
}
__device__ __forceinline__ uint2 f4_to_bf4(float4 a) {
    uint2 v;
    v.x = f2bf(a.x) | (f2bf(a.y) << 16);
    v.y = f2bf(a.z) | (f2bf(a.w) << 16);
    return v;
}

// ---------------- block scan helper (256 threads, 4 waves) ----------------
__device__ __forceinline__ int block_excl_scan256(int v, int t) {
    __shared__ int ws[4];
    int lane = t & 63, w = t >> 6;
    int x = v;
    #pragma unroll
    for (int off = 1; off < 64; off <<= 1) {
        int y = __shfl_up(x, off, 64);
        if (lane >= off) x += y;
    }
    if (lane == 63) ws[w] = x;
    __syncthreads();
    int b0 = ws[0], b1 = ws[1], b2 = ws[2];
    int wbase = (w > 0 ? b0 : 0) + (w > 1 ? b1 : 0) + (w > 2 ? b2 : 0);
    return wbase + x - v;  // exclusive
}

// ---------------- CSR build ----------------
__global__ void k_degree(const int* __restrict__ dst, int* __restrict__ cnt) {
    int i = (blockIdx.x * blockDim.x + threadIdx.x) * 4;
    if (i + 3 < N_EDGES) {
        int4 d = *(const int4*)&dst[i];
        atomicAdd(&cnt[d.x], 1);
        atomicAdd(&cnt[d.y], 1);
        atomicAdd(&cnt[d.z], 1);
        atomicAdd(&cnt[d.w], 1);
    } else {
        for (int e = i; e < N_EDGES; e++) atomicAdd(&cnt[dst[e]], 1);
    }
}

#define SCAN_NB ((N_NODES + 255) / 256)  // 196

__global__ void k_scan_part(const int* __restrict__ cnt, int* __restrict__ part) {
    __shared__ int ws[4];
    int t = threadIdx.x;
    int i = blockIdx.x * 256 + t;
    int v = (i < N_NODES) ? cnt[i] : 0;
    int lane = t & 63, w = t >> 6;
    #pragma unroll
    for (int off = 1; off < 64; off <<= 1) v += __shfl_xor(v, off, 64);
    if (lane == 0) ws[w] = v;
    __syncthreads();
    if (t == 0) part[blockIdx.x] = ws[0] + ws[1] + ws[2] + ws[3];
}

__global__ void k_scan_mid(int* __restrict__ part, int* __restrict__ offs) {
    int t = threadIdx.x;
    int v = (t < SCAN_NB) ? part[t] : 0;
    int ex = block_excl_scan256(v, t);
    if (t < SCAN_NB) part[t] = ex;
    if (t == 255) offs[N_NODES] = ex + v;
}

__global__ void k_scan_add(const int* __restrict__ cnt, const int* __restrict__ part,
                           int* __restrict__ offs, int* __restrict__ offs2,
                           float* __restrict__ dis) {
    int t = threadIdx.x;
    int i = blockIdx.x * 256 + t;
    int v = (i < N_NODES) ? cnt[i] : 0;
    int ex = block_excl_scan256(v, t);
    if (i < N_NODES) {
        int o = part[blockIdx.x] + ex;
        offs[i] = o;
        offs2[i] = o;
        dis[i] = rsqrtf((float)v + 1.0f);
    }
}

// payload: (src, dis[src]) packed 8B; dn factored out at aggregation time
__global__ void k_fillcsr(const int* __restrict__ src, const int* __restrict__ dst,
                          const float* __restrict__ dis, int* __restrict__ offs2,
                          int2* __restrict__ csr) {
    int i = (blockIdx.x * blockDim.x + threadIdx.x) * 4;
    if (i + 3 < N_EDGES) {
        int4 s4 = *(const int4*)&src[i];
        int4 d4 = *(const int4*)&dst[i];
        int p0 = atomicAdd(&offs2[d4.x], 1);
        int p1 = atomicAdd(&offs2[d4.y], 1);
        int p2 = atomicAdd(&offs2[d4.z], 1);
        int p3 = atomicAdd(&offs2[d4.w], 1);
        csr[p0] = make_int2(s4.x, __float_as_int(dis[s4.x]));
        csr[p1] = make_int2(s4.y, __float_as_int(dis[s4.y]));
        csr[p2] = make_int2(s4.z, __float_as_int(dis[s4.z]));
        csr[p3] = make_int2(s4.w, __float_as_int(dis[s4.w]));
    } else {
        for (int e = i; e < N_EDGES; e++) {
            int s = src[e], d = dst[e];
            int p = atomicAdd(&offs2[d], 1);
            csr[p] = make_int2(s, __float_as_int(dis[s]));
        }
    }
}

// ---------------- layer 1 in 9-dim space ----------------
__global__ void k_pad(const float* __restrict__ x, float* __restrict__ x16,
                      const int* __restrict__ batch, int* __restrict__ counts) {
    int idx = blockIdx.x * blockDim.x + threadIdx.x;
    if (idx >= N_NODES * 16) return;
    int n = idx >> 4, f = idx & 15;
    x16[idx] = (f < 9) ? x[n * 9 + f] : 0.f;
    if (f == 0) atomicAdd(&counts[batch[n]], 1);
}

// y[n] = dn * sum_e dis_s*x16[src] + dn^2*x16[n]
__global__ __launch_bounds__(256) void k_agg9(const float* __restrict__ x16,
                                              const int* __restrict__ offs,
                                              const int2* __restrict__ csr,
                                              const float* __restrict__ dis,
                                              float* __restrict__ y) {
    int wv = threadIdx.x >> 6, lane = threadIdx.x & 63;
    int n = blockIdx.x * 4 + wv;
    if (n >= N_NODES) return;
    int slot = lane >> 4, fl = lane & 15;
    int e0 = offs[n], e1 = offs[n + 1];
    float acc = 0.f;
    for (int e = e0 + slot; e < e1; e += 16) {
        int ss[4]; float cc[4];
        #pragma unroll
        for (int i = 0; i < 4; i++) {
            int ei = e + i * 4;
            bool ok = ei < e1;
            int2 v = ok ? csr[ei] : make_int2(n, 0);
            ss[i] = v.x;
            cc[i] = __int_as_float(v.y);
        }
        #pragma unroll
        for (int i = 0; i < 4; i++)
            acc += cc[i] * x16[(size_t)ss[i] * 16 + fl];
    }
    acc += __shfl_xor(acc, 16, 64);
    acc += __shfl_xor(acc, 32, 64);
    float dn = dis[n];
    acc = dn * acc + dn * dn * x16[(size_t)n * 16 + fl];
    if (slot == 0) y[(size_t)n * 16 + fl] = acc;
}

// h1 = relu(y @ W1 + b1)   y:[N,16] (9 used), W1:[9,128]  -> fp32
__global__ void k_gemm1(const float* __restrict__ y16, const float* __restrict__ W1,
                        const float* __restrict__ b1, float* __restrict__ out) {
    int idx = blockIdx.x * blockDim.x + threadIdx.x;
    if (idx >= N_NODES * HID) return;
    int n = idx >> 7, j = idx & 127;
    const float* yr = y16 + (size_t)n * 16;
    float acc = b1[j];
    #pragma unroll
    for (int k = 0; k < 9; k++) acc += yr[k] * W1[k * HID + j];
    out[idx] = fmaxf(acc, 0.f);
}

// ---------------- 128-dim layers ----------------
// h[N,128]f32 @ W[128,128] -> out[N,128] bf16
__global__ __launch_bounds__(256) void k_gemm128(const float* __restrict__ h,
                                                 const float* __restrict__ W,
                                                 unsigned* __restrict__ out_bf) {
    __shared__ float htile[64 * 128];
    int t = threadIdx.x;
    int n0 = blockIdx.x * 64;
    for (int i = t; i < 64 * 128; i += 256) {
        int n = n0 + (i >> 7);
        htile[i] = (n < N_NODES) ? h[(size_t)n0 * 128 + i] : 0.f;
    }
    __syncthreads();
    int q = t & 31;
    int tn = t >> 5;
    float4 acc[8];
    #pragma unroll
    for (int r = 0; r < 8; r++) acc[r] = make_float4(0.f, 0.f, 0.f, 0.f);
    const float4* W4 = (const float4*)W;
    for (int k = 0; k < 128; k += 2) {
        float4 w0 = W4[k * 32 + q];
        float4 w1 = W4[(k + 1) * 32 + q];
        #pragma unroll
        for (int r = 0; r < 8; r++) {
            int row = tn * 8 + r;
            float2 hk = *(const float2*)&htile[row * 128 + k];
            acc[r].x += hk.x * w0.x; acc[r].y += hk.x * w0.y;
            acc[r].z += hk.x * w0.z; acc[r].w += hk.x * w0.w;
            acc[r].x += hk.y * w1.x; acc[r].y += hk.y * w1.y;
            acc[r].z += hk.y * w1.z; acc[r].w += hk.y * w1.w;
        }
    }
    uint2* out8 = (uint2*)out_bf;
    #pragma unroll
    for (int r = 0; r < 8; r++) {
        int n = n0 + tn * 8 + r;
        if (n < N_NODES) out8[(size_t)n * 32 + q] = f4_to_bf4(acc[r]);
    }
}

// wave-per-node gather-agg on bf16 rows: lane = 4 bf16 (8B), 32 lanes/row,
// 2 edges per load slot, 16 edges in flight
template <int OUT_BF16, int RELU, int HAS_BIAS>
__global__ __launch_bounds__(256) void k_agg_t(const uint2* __restrict__ h8,
                                               const int* __restrict__ offs,
                                               const int2* __restrict__ csr,
                                               const float* __restrict__ dis,
                                               const float* __restrict__ bias,
                                               void* __restrict__ out) {
    int wv = threadIdx.x >> 6, lane = threadIdx.x & 63;
    int n = blockIdx.x * 4 + wv;
    if (n >= N_NODES) return;
    int half = lane >> 5;
    int fl = lane & 31;
    int e0 = offs[n], e1 = offs[n + 1];
    float4 acc = make_float4(0.f, 0.f, 0.f, 0.f);
    for (int e = e0 + half; e < e1; e += 16) {
        int ss[8]; float cc[8];
        #pragma unroll
        for (int i = 0; i < 8; i++) {
            int ei = e + i * 2;
            bool ok = ei < e1;
            int2 v = ok ? csr[ei] : make_int2(n, 0);
            ss[i] = v.x;
            cc[i] = __int_as_float(v.y);
        }
        uint2 rows[8];
        #pragma unroll
        for (int i = 0; i < 8; i++)
            rows[i] = h8[(size_t)ss[i] * 32 + fl];
        #pragma unroll
        for (int i = 0; i < 8; i++) {
            float4 r = bf4_to_f4(rows[i]);
            acc.x += cc[i] * r.x;
            acc.y += cc[i] * r.y;
            acc.z += cc[i] * r.z;
            acc.w += cc[i] * r.w;
        }
    }
    acc.x += __shfl_xor(acc.x, 32, 64);
    acc.y += __shfl_xor(acc.y, 32, 64);
    acc.z += __shfl_xor(acc.z, 32, 64);
    acc.w += __shfl_xor(acc.w, 32, 64);
    float dn = dis[n];
    float4 hv = bf4_to_f4(h8[(size_t)n * 32 + fl]);
    acc.x = dn * acc.x + dn * dn * hv.x;
    acc.y = dn * acc.y + dn * dn * hv.y;
    acc.z = dn * acc.z + dn * dn * hv.z;
    acc.w = dn * acc.w + dn * dn * hv.w;
    if (HAS_BIAS) {
        float4 bb = ((const float4*)bias)[fl];
        acc.x += bb.x; acc.y += bb.y; acc.z += bb.z; acc.w += bb.w;
    }
    if (RELU) {
        acc.x = fmaxf(acc.x, 0.f);
        acc.y = fmaxf(acc.y, 0.f);
        acc.z = fmaxf(acc.z, 0.f);
        acc.w = fmaxf(acc.w, 0.f);
    }
    if (half == 0) {
        if (OUT_BF16)
            ((uint2*)out)[(size_t)n * 32 + fl] = f4_to_bf4(acc);
        else
            ((float4*)out)[(size_t)n * 32 + fl] = acc;
    }
}

// ---------------- pooling ----------------
__global__ void k_pool(const float* __restrict__ X, const int* __restrict__ batch,
                       float* __restrict__ sums) {
    int f = threadIdx.x;
    int n0 = blockIdx.x * 16;
    int gprev = -1;
    float acc = 0.f;
    for (int i = 0; i < 16; i++) {
        int n = n0 + i;
        if (n >= N_NODES) break;
        int g = batch[n];
        float v = X[(size_t)n * 128 + f];
        if (g != gprev) {
            if (gprev >= 0) atomicAdd(&sums[gprev * 128 + f], acc);
            acc = 0.f;
            gprev = g;
        }
        acc += v;
    }
    if (gprev >= 0) atomicAdd(&sums[gprev * 128 + f], acc);
}

__global__ void k_final(const float* __restrict__ sums, const int* __restrict__ counts,
                        const float* __restrict__ W3, const float* __restrict__ b3,
                        float* __restrict__ out) {
    int idx = blockIdx.x * blockDim.x + threadIdx.x;
    if (idx >= N_GRAPHS * HID) return;
    int g = idx >> 7, j = idx & 127;
    float inv = 1.0f / fmaxf((float)counts[g], 1.0f);
    const float* srow = sums + g * 128;
    float acc = 0.f;
    for (int k = 0; k < 128; k++) acc += srow[k] * W3[k * 128 + j];
    out[idx] = acc * inv + b3[j];
}

extern "C" void kernel_launch(void* const* d_in, const int* in_sizes, int n_in,
                              void* d_out, int out_size, void* d_ws, size_t ws_size,
                              hipStream_t stream) {
    const float* x     = (const float*)d_in[0];
    const int*   ei    = (const int*)d_in[1];
    const int*   batch = (const int*)d_in[2];
    const float* W1    = (const float*)d_in[3];
    const float* b1    = (const float*)d_in[4];
    const float* W2    = (const float*)d_in[5];
    const float* b2    = (const float*)d_in[6];
    const float* W3    = (const float*)d_in[7];
    const float* b3    = (const float*)d_in[8];
    float* out = (float*)d_out;
    const int* src = ei;
    const int* dst = ei + N_EDGES;

    char* ws = (char*)d_ws;
    size_t off = 0;
    auto alloc = [&](size_t bytes) -> void* {
        void* p = ws + off;
        off += (bytes + 255) & ~(size_t)255;
        return p;
    };
    float*    bufA  = (float*)alloc((size_t)N_NODES * 128 * 4);    // fp32 h1 / X
    unsigned* hb1   = (unsigned*)alloc((size_t)N_NODES * 64 * 4);  // bf16 [N,128]
    unsigned* hb2   = (unsigned*)alloc((size_t)N_NODES * 64 * 4);  // bf16 [N,128]
    int2*  csr      = (int2*)alloc((size_t)N_EDGES * 8);
    int*   cnt      = (int*)alloc((size_t)N_NODES * 4);
    int*   offs     = (int*)alloc((size_t)(N_NODES + 1) * 4);
    int*   offs2    = (int*)alloc((size_t)N_NODES * 4);
    float* dis      = (float*)alloc((size_t)N_NODES * 4);
    float* sums     = (float*)alloc((size_t)N_GRAPHS * 128 * 4);
    int*   counts   = (int*)alloc((size_t)N_GRAPHS * 4);
    float* x16      = (float*)alloc((size_t)N_NODES * 16 * 4);
    float* y16      = (float*)alloc((size_t)N_NODES * 16 * 4);
    int*   part     = (int*)alloc((size_t)SCAN_NB * 4);

    hipMemsetAsync(cnt, 0, (size_t)N_NODES * 4, stream);
    hipMemsetAsync(sums, 0, (size_t)N_GRAPHS * 128 * 4, stream);
    hipMemsetAsync(counts, 0, (size_t)N_GRAPHS * 4, stream);

    k_degree<<<(N_EDGES / 4 + 255) / 256, 256, 0, stream>>>(dst, cnt);
    k_scan_part<<<SCAN_NB, 256, 0, stream>>>(cnt, part);
    k_scan_mid<<<1, 256, 0, stream>>>(part, offs);
    k_scan_add<<<SCAN_NB, 256, 0, stream>>>(cnt, part, offs, offs2, dis);
    k_fillcsr<<<(N_EDGES / 4 + 255) / 256, 256, 0, stream>>>(src, dst, dis, offs2, csr);
    k_pad<<<(N_NODES * 16 + 255) / 256, 256, 0, stream>>>(x, x16, batch, counts);

    // layer 1: aggregate in 9-dim space, then h1 = relu(y @ W1 + b1)  (fp32)
    k_agg9<<<(N_NODES + 3) / 4, 256, 0, stream>>>(x16, offs, csr, dis, y16);
    k_gemm1<<<(N_NODES * HID + 255) / 256, 256, 0, stream>>>(y16, W1, b1, bufA);
    // layer 2: hb1 = bf16(h1@W2); hb2 = bf16(relu(agg(hb1) + b2))
    k_gemm128<<<(N_NODES + 63) / 64, 256, 0, stream>>>(bufA, W2, hb1);
    k_agg_t<1, 1, 1><<<(N_NODES + 3) / 4, 256, 0, stream>>>((const uint2*)hb1, offs, csr,
                                                            dis, b2, hb2);
    // layer 3 (W3 deferred past pooling): X = agg(hb2) (fp32)
    k_agg_t<0, 0, 0><<<(N_NODES + 3) / 4, 256, 0, stream>>>((const uint2*)hb2, offs, csr,
                                                            dis, nullptr, bufA);
    // pool + final tiny GEMM
    k_pool<<<(N_NODES + 15) / 16, 128, 0, stream>>>(bufA, batch, sums);
    k_final<<<(N_GRAPHS * HID + 255) / 256, 256, 0, stream>>>(sums, counts, W3, b3, out);
}

// Round 5
// 393.548 us; speedup vs baseline: 2.0631x; 1.2468x over previous
//
#include <hip/hip_runtime.h>

#define N_NODES 50000
#define N_EDGES 1600000
#define N_GRAPHS 256
#define HID 128

#define NBUCK 256
#define BUCK_SHIFT 8
#define NBUCK_USED ((N_NODES + 255) >> 8)   // 196
#define BINBLK 4096                          // edges per block in hist/binfill

// ---------------- bf16 helpers ----------------
__device__ __forceinline__ float4 bf4_to_f4(uint2 v) {
    float4 r;
    r.x = __uint_as_float(v.x << 16);
    r.y = __uint_as_float(v.x & 0xffff0000u);
    r.z = __uint_as_float(v.y << 16);
    r.w = __uint_as_float(v.y & 0xffff0000u);
    return r;
}
__device__ __forceinline__ unsigned f2bf(float f) {
    unsigned u = __float_as_uint(f);
    return (u + 0x7fffu + ((u >> 16) & 1u)) >> 16;
}
__device__ __forceinline__ uint2 f4_to_bf4(float4 a) {
    uint2 v;
    v.x = f2bf(a.x) | (f2bf(a.y) << 16);
    v.y = f2bf(a.z) | (f2bf(a.w) << 16);
    return v;
}

// ---------------- block scan helper (256 threads, 4 waves) ----------------
__device__ __forceinline__ int block_excl_scan256(int v, int t) {
    __shared__ int ws[4];
    int lane = t & 63, w = t >> 6;
    int x = v;
    #pragma unroll
    for (int off = 1; off < 64; off <<= 1) {
        int y = __shfl_up(x, off, 64);
        if (lane >= off) x += y;
    }
    if (lane == 63) ws[w] = x;
    __syncthreads();
    int b0 = ws[0], b1 = ws[1], b2 = ws[2];
    int wbase = (w > 0 ? b0 : 0) + (w > 1 ? b1 : 0) + (w > 2 ? b2 : 0);
    return wbase + x - v;  // exclusive
}

// ---------------- bucketed CSR build ----------------
__global__ __launch_bounds__(256) void k_bhist(const int* __restrict__ dst,
                                               int* __restrict__ bhist) {
    __shared__ int h[NBUCK];
    int t = threadIdx.x;
    h[t] = 0;
    __syncthreads();
    int base = blockIdx.x * BINBLK;
    #pragma unroll
    for (int i = 0; i < 16; i++) {
        int e = base + i * 256 + t;
        if (e < N_EDGES) atomicAdd(&h[dst[e] >> BUCK_SHIFT], 1);
    }
    __syncthreads();
    if (h[t]) atomicAdd(&bhist[t], h[t]);
}

__global__ void k_bscan(const int* __restrict__ bhist, int* __restrict__ bstart,
                        int* __restrict__ bfill) {
    int t = threadIdx.x;
    int v = bhist[t];
    int ex = block_excl_scan256(v, t);
    bstart[t] = ex;
    bfill[t] = ex;
    if (t == 255) bstart[NBUCK] = ex + v;  // == N_EDGES
}

// bin edges into bucket regions of temp[] (writes confined to ~128B runs per bucket)
__global__ __launch_bounds__(256) void k_binfill(const int* __restrict__ src,
                                                 const int* __restrict__ dst,
                                                 int* __restrict__ bfill,
                                                 int2* __restrict__ temp) {
    __shared__ int h[NBUCK], gp[NBUCK], rk[NBUCK];
    int t = threadIdx.x;
    h[t] = 0; rk[t] = 0;
    __syncthreads();
    int base = blockIdx.x * BINBLK;
    int ss[16], dd[16];
    #pragma unroll
    for (int i = 0; i < 16; i++) {
        int e = base + i * 256 + t;
        bool ok = e < N_EDGES;
        ss[i] = ok ? src[e] : 0;
        dd[i] = ok ? dst[e] : -1;
        if (ok) atomicAdd(&h[dd[i] >> BUCK_SHIFT], 1);
    }
    __syncthreads();
    if (h[t]) gp[t] = atomicAdd(&bfill[t], h[t]);
    __syncthreads();
    #pragma unroll
    for (int i = 0; i < 16; i++) {
        if (dd[i] >= 0) {
            int b = dd[i] >> BUCK_SHIFT;
            int r = atomicAdd(&rk[b], 1);
            temp[gp[b] + r] = make_int2(ss[i], dd[i]);
        }
    }
}

// one block per bucket: per-node counts/offsets/dis in LDS, then confined scatter
__global__ __launch_bounds__(256) void k_csrbuild(const int2* __restrict__ temp,
                                                  const int* __restrict__ bstart,
                                                  int* __restrict__ offs,
                                                  float* __restrict__ dis,
                                                  int* __restrict__ csr_src) {
    __shared__ int cnt[256], loff[256], rk[256];
    int b = blockIdx.x, t = threadIdx.x;
    int e0 = bstart[b], e1 = bstart[b + 1];
    int n0 = b << BUCK_SHIFT;
    cnt[t] = 0; rk[t] = 0;
    __syncthreads();
    for (int e = e0 + t; e < e1; e += 256)
        atomicAdd(&cnt[temp[e].y - n0], 1);
    __syncthreads();
    int c = cnt[t];
    int ex = block_excl_scan256(c, t);
    loff[t] = ex;
    int n = n0 + t;
    if (n < N_NODES) {
        offs[n] = e0 + ex;
        dis[n] = rsqrtf((float)c + 1.0f);
    }
    if (b == 0 && t == 0) offs[N_NODES] = N_EDGES;
    __syncthreads();
    for (int e = e0 + t; e < e1; e += 256) {
        int2 v = temp[e];
        int li = v.y - n0;
        int r = atomicAdd(&rk[li], 1);
        csr_src[e0 + loff[li] + r] = v.x;
    }
}

// ---------------- layer 1 in 9-dim space ----------------
__global__ void k_pad(const float* __restrict__ x, float* __restrict__ x16,
                      const int* __restrict__ batch, int* __restrict__ counts) {
    int idx = blockIdx.x * blockDim.x + threadIdx.x;
    if (idx >= N_NODES * 16) return;
    int n = idx >> 4, f = idx & 15;
    x16[idx] = (f < 9) ? x[n * 9 + f] : 0.f;
    if (f == 0) atomicAdd(&counts[batch[n]], 1);
}

// y[n] = dn * sum_e dis_s*x16[src] + dn^2*x16[n]
__global__ __launch_bounds__(256) void k_agg9(const float* __restrict__ x16,
                                              const int* __restrict__ offs,
                                              const int* __restrict__ csr_src,
                                              const float* __restrict__ dis,
                                              float* __restrict__ y) {
    int wv = threadIdx.x >> 6, lane = threadIdx.x & 63;
    int n = blockIdx.x * 4 + wv;
    if (n >= N_NODES) return;
    int slot = lane >> 4, fl = lane & 15;
    int e0 = offs[n], e1 = offs[n + 1];
    float acc = 0.f;
    for (int e = e0 + slot; e < e1; e += 16) {
        int ss[4]; float cc[4];
        #pragma unroll
        for (int i = 0; i < 4; i++) {
            int ei = e + i * 4;
            bool ok = ei < e1;
            ss[i] = ok ? csr_src[ei] : n;
            cc[i] = ok ? dis[ss[i]] : 0.f;
        }
        #pragma unroll
        for (int i = 0; i < 4; i++)
            acc += cc[i] * x16[(size_t)ss[i] * 16 + fl];
    }
    acc += __shfl_xor(acc, 16, 64);
    acc += __shfl_xor(acc, 32, 64);
    float dn = dis[n];
    acc = dn * acc + dn * dn * x16[(size_t)n * 16 + fl];
    if (slot == 0) y[(size_t)n * 16 + fl] = acc;
}

// h1 = relu(y @ W1 + b1)   y:[N,16] (9 used), W1:[9,128]  -> fp32
__global__ void k_gemm1(const float* __restrict__ y16, const float* __restrict__ W1,
                        const float* __restrict__ b1, float* __restrict__ out) {
    int idx = blockIdx.x * blockDim.x + threadIdx.x;
    if (idx >= N_NODES * HID) return;
    int n = idx >> 7, j = idx & 127;
    const float* yr = y16 + (size_t)n * 16;
    float acc = b1[j];
    #pragma unroll
    for (int k = 0; k < 9; k++) acc += yr[k] * W1[k * HID + j];
    out[idx] = fmaxf(acc, 0.f);
}

// ---------------- 128-dim layers ----------------
// h[N,128]f32 @ W[128,128] -> out[N,128] bf16
__global__ __launch_bounds__(256) void k_gemm128(const float* __restrict__ h,
                                                 const float* __restrict__ W,
                                                 unsigned* __restrict__ out_bf) {
    __shared__ float htile[64 * 128];
    int t = threadIdx.x;
    int n0 = blockIdx.x * 64;
    for (int i = t; i < 64 * 128; i += 256) {
        int n = n0 + (i >> 7);
        htile[i] = (n < N_NODES) ? h[(size_t)n0 * 128 + i] : 0.f;
    }
    __syncthreads();
    int q = t & 31;
    int tn = t >> 5;
    float4 acc[8];
    #pragma unroll
    for (int r = 0; r < 8; r++) acc[r] = make_float4(0.f, 0.f, 0.f, 0.f);
    const float4* W4 = (const float4*)W;
    for (int k = 0; k < 128; k += 2) {
        float4 w0 = W4[k * 32 + q];
        float4 w1 = W4[(k + 1) * 32 + q];
        #pragma unroll
        for (int r = 0; r < 8; r++) {
            int row = tn * 8 + r;
            float2 hk = *(const float2*)&htile[row * 128 + k];
            acc[r].x += hk.x * w0.x; acc[r].y += hk.x * w0.y;
            acc[r].z += hk.x * w0.z; acc[r].w += hk.x * w0.w;
            acc[r].x += hk.y * w1.x; acc[r].y += hk.y * w1.y;
            acc[r].z += hk.y * w1.z; acc[r].w += hk.y * w1.w;
        }
    }
    uint2* out8 = (uint2*)out_bf;
    #pragma unroll
    for (int r = 0; r < 8; r++) {
        int n = n0 + tn * 8 + r;
        if (n < N_NODES) out8[(size_t)n * 32 + q] = f4_to_bf4(acc[r]);
    }
}

// wave-per-node gather-agg on bf16 rows: lane = 4 bf16 (8B), 32 lanes/row,
// 2 edges per load slot, 16 edges in flight; coef gathered from L2-resident dis
template <int OUT_BF16, int RELU, int HAS_BIAS>
__global__ __launch_bounds__(256) void k_agg_t(const uint2* __restrict__ h8,
                                               const int* __restrict__ offs,
                                               const int* __restrict__ csr_src,
                                               const float* __restrict__ dis,
                                               const float* __restrict__ bias,
                                               void* __restrict__ out) {
    int wv = threadIdx.x >> 6, lane = threadIdx.x & 63;
    int n = blockIdx.x * 4 + wv;
    if (n >= N_NODES) return;
    int half = lane >> 5;
    int fl = lane & 31;
    int e0 = offs[n], e1 = offs[n + 1];
    float4 acc = make_float4(0.f, 0.f, 0.f, 0.f);
    for (int e = e0 + half; e < e1; e += 16) {
        int ss[8]; float cc[8];
        #pragma unroll
        for (int i = 0; i < 8; i++) {
            int ei = e + i * 2;
            bool ok = ei < e1;
            ss[i] = ok ? csr_src[ei] : n;
            cc[i] = ok ? dis[ss[i]] : 0.f;
        }
        uint2 rows[8];
        #pragma unroll
        for (int i = 0; i < 8; i++)
            rows[i] = h8[(size_t)ss[i] * 32 + fl];
        #pragma unroll
        for (int i = 0; i < 8; i++) {
            float4 r = bf4_to_f4(rows[i]);
            acc.x += cc[i] * r.x;
            acc.y += cc[i] * r.y;
            acc.z += cc[i] * r.z;
            acc.w += cc[i] * r.w;
        }
    }
    acc.x += __shfl_xor(acc.x, 32, 64);
    acc.y += __shfl_xor(acc.y, 32, 64);
    acc.z += __shfl_xor(acc.z, 32, 64);
    acc.w += __shfl_xor(acc.w, 32, 64);
    float dn = dis[n];
    float4 hv = bf4_to_f4(h8[(size_t)n * 32 + fl]);
    acc.x = dn * acc.x + dn * dn * hv.x;
    acc.y = dn * acc.y + dn * dn * hv.y;
    acc.z = dn * acc.z + dn * dn * hv.z;
    acc.w = dn * acc.w + dn * dn * hv.w;
    if (HAS_BIAS) {
        float4 bb = ((const float4*)bias)[fl];
        acc.x += bb.x; acc.y += bb.y; acc.z += bb.z; acc.w += bb.w;
    }
    if (RELU) {
        acc.x = fmaxf(acc.x, 0.f);
        acc.y = fmaxf(acc.y, 0.f);
        acc.z = fmaxf(acc.z, 0.f);
        acc.w = fmaxf(acc.w, 0.f);
    }
    if (half == 0) {
        if (OUT_BF16)
            ((uint2*)out)[(size_t)n * 32 + fl] = f4_to_bf4(acc);
        else
            ((float4*)out)[(size_t)n * 32 + fl] = acc;
    }
}

// ---------------- pooling ----------------
__global__ void k_pool(const float* __restrict__ X, const int* __restrict__ batch,
                       float* __restrict__ sums) {
    int f = threadIdx.x;
    int n0 = blockIdx.x * 16;
    int gprev = -1;
    float acc = 0.f;
    for (int i = 0; i < 16; i++) {
        int n = n0 + i;
        if (n >= N_NODES) break;
        int g = batch[n];
        float v = X[(size_t)n * 128 + f];
        if (g != gprev) {
            if (gprev >= 0) atomicAdd(&sums[gprev * 128 + f], acc);
            acc = 0.f;
            gprev = g;
        }
        acc += v;
    }
    if (gprev >= 0) atomicAdd(&sums[gprev * 128 + f], acc);
}

__global__ void k_final(const float* __restrict__ sums, const int* __restrict__ counts,
                        const float* __restrict__ W3, const float* __restrict__ b3,
                        float* __restrict__ out) {
    int idx = blockIdx.x * blockDim.x + threadIdx.x;
    if (idx >= N_GRAPHS * HID) return;
    int g = idx >> 7, j = idx & 127;
    float inv = 1.0f / fmaxf((float)counts[g], 1.0f);
    const float* srow = sums + g * 128;
    float acc = 0.f;
    for (int k = 0; k < 128; k++) acc += srow[k] * W3[k * 128 + j];
    out[idx] = acc * inv + b3[j];
}

extern "C" void kernel_launch(void* const* d_in, const int* in_sizes, int n_in,
                              void* d_out, int out_size, void* d_ws, size_t ws_size,
                              hipStream_t stream) {
    const float* x     = (const float*)d_in[0];
    const int*   ei    = (const int*)d_in[1];
    const int*   batch = (const int*)d_in[2];
    const float* W1    = (const float*)d_in[3];
    const float* b1    = (const float*)d_in[4];
    const float* W2    = (const float*)d_in[5];
    const float* b2    = (const float*)d_in[6];
    const float* W3    = (const float*)d_in[7];
    const float* b3    = (const float*)d_in[8];
    float* out = (float*)d_out;
    const int* src = ei;
    const int* dst = ei + N_EDGES;

    char* ws = (char*)d_ws;
    size_t off = 0;
    auto alloc = [&](size_t bytes) -> void* {
        void* p = ws + off;
        off += (bytes + 255) & ~(size_t)255;
        return p;
    };
    float*    bufA    = (float*)alloc((size_t)N_NODES * 128 * 4);    // fp32 h1 / X
    unsigned* hb1     = (unsigned*)alloc((size_t)N_NODES * 64 * 4);  // bf16 [N,128]
    unsigned* hb2     = (unsigned*)alloc((size_t)N_NODES * 64 * 4);  // bf16 [N,128]
    int2*     temp    = (int2*)alloc((size_t)N_EDGES * 8);           // binned (src,dst)
    int*      csr_src = (int*)alloc((size_t)N_EDGES * 4);
    int*      bhist   = (int*)alloc((size_t)NBUCK * 4);
    int*      bstart  = (int*)alloc((size_t)(NBUCK + 1) * 4);
    int*      bfill   = (int*)alloc((size_t)NBUCK * 4);
    int*      offs    = (int*)alloc((size_t)(N_NODES + 1) * 4);
    float*    dis     = (float*)alloc((size_t)N_NODES * 4);
    float*    sums    = (float*)alloc((size_t)N_GRAPHS * 128 * 4);
    int*      counts  = (int*)alloc((size_t)N_GRAPHS * 4);
    float*    x16     = (float*)alloc((size_t)N_NODES * 16 * 4);
    float*    y16     = (float*)alloc((size_t)N_NODES * 16 * 4);

    hipMemsetAsync(bhist, 0, (size_t)NBUCK * 4, stream);
    hipMemsetAsync(sums, 0, (size_t)N_GRAPHS * 128 * 4, stream);
    hipMemsetAsync(counts, 0, (size_t)N_GRAPHS * 4, stream);

    const int binGrid = (N_EDGES + BINBLK - 1) / BINBLK;  // 391
    k_bhist<<<binGrid, 256, 0, stream>>>(dst, bhist);
    k_bscan<<<1, 256, 0, stream>>>(bhist, bstart, bfill);
    k_binfill<<<binGrid, 256, 0, stream>>>(src, dst, bfill, temp);
    k_csrbuild<<<NBUCK_USED, 256, 0, stream>>>(temp, bstart, offs, dis, csr_src);
    k_pad<<<(N_NODES * 16 + 255) / 256, 256, 0, stream>>>(x, x16, batch, counts);

    // layer 1: aggregate in 9-dim space, then h1 = relu(y @ W1 + b1)  (fp32)
    k_agg9<<<(N_NODES + 3) / 4, 256, 0, stream>>>(x16, offs, csr_src, dis, y16);
    k_gemm1<<<(N_NODES * HID + 255) / 256, 256, 0, stream>>>(y16, W1, b1, bufA);
    // layer 2: hb1 = bf16(h1@W2); hb2 = bf16(relu(agg(hb1) + b2))
    k_gemm128<<<(N_NODES + 63) / 64, 256, 0, stream>>>(bufA, W2, hb1);
    k_agg_t<1, 1, 1><<<(N_NODES + 3) / 4, 256, 0, stream>>>((const uint2*)hb1, offs,
                                                            csr_src, dis, b2, hb2);
    // layer 3 (W3 deferred past pooling): X = agg(hb2) (fp32)
    k_agg_t<0, 0, 0><<<(N_NODES + 3) / 4, 256, 0, stream>>>((const uint2*)hb2, offs,
                                                            csr_src, dis, nullptr, bufA);
    // pool + final tiny GEMM
    k_pool<<<(N_NODES + 15) / 16, 128, 0, stream>>>(bufA, batch, sums);
    k_final<<<(N_GRAPHS * HID + 255) / 256, 256, 0, stream>>>(sums, counts, W3, b3, out);
}

// Round 6
// 284.554 us; speedup vs baseline: 2.8534x; 1.3830x over previous
//
#include <hip/hip_runtime.h>

#define N_NODES 50000
#define N_EDGES 1600000
#define N_GRAPHS 256
#define HID 128

#define NBUCK 256
#define BUCK_SHIFT 8
#define NBUCK_USED ((N_NODES + 255) >> 8)   // 196
#define BINBLK 4096                          // edges per block in hist/binfill

// ---------------- bf16 helpers ----------------
__device__ __forceinline__ float4 bf4_to_f4(uint2 v) {
    float4 r;
    r.x = __uint_as_float(v.x << 16);
    r.y = __uint_as_float(v.x & 0xffff0000u);
    r.z = __uint_as_float(v.y << 16);
    r.w = __uint_as_float(v.y & 0xffff0000u);
    return r;
}
__device__ __forceinline__ unsigned f2bf(float f) {
    unsigned u = __float_as_uint(f);
    return (u + 0x7fffu + ((u >> 16) & 1u)) >> 16;
}
__device__ __forceinline__ uint2 f4_to_bf4(float4 a) {
    uint2 v;
    v.x = f2bf(a.x) | (f2bf(a.y) << 16);
    v.y = f2bf(a.z) | (f2bf(a.w) << 16);
    return v;
}

// ---------------- block scan helper (256 threads, 4 waves) ----------------
__device__ __forceinline__ int block_excl_scan256(int v, int t) {
    __shared__ int ws[4];
    int lane = t & 63, w = t >> 6;
    int x = v;
    #pragma unroll
    for (int off = 1; off < 64; off <<= 1) {
        int y = __shfl_up(x, off, 64);
        if (lane >= off) x += y;
    }
    if (lane == 63) ws[w] = x;
    __syncthreads();
    int b0 = ws[0], b1 = ws[1], b2 = ws[2];
    int wbase = (w > 0 ? b0 : 0) + (w > 1 ? b1 : 0) + (w > 2 ? b2 : 0);
    return wbase + x - v;  // exclusive
}

// ---------------- bucketed CSR build ----------------
__global__ __launch_bounds__(256) void k_bhist(const int* __restrict__ dst,
                                               int* __restrict__ bhist) {
    __shared__ int h[NBUCK];
    int t = threadIdx.x;
    h[t] = 0;
    __syncthreads();
    int base = blockIdx.x * BINBLK;
    #pragma unroll
    for (int i = 0; i < 16; i++) {
        int e = base + i * 256 + t;
        if (e < N_EDGES) atomicAdd(&h[dst[e] >> BUCK_SHIFT], 1);
    }
    __syncthreads();
    if (h[t]) atomicAdd(&bhist[t], h[t]);
}

__global__ void k_bscan(const int* __restrict__ bhist, int* __restrict__ bstart,
                        int* __restrict__ bfill) {
    int t = threadIdx.x;
    int v = bhist[t];
    int ex = block_excl_scan256(v, t);
    bstart[t] = ex;
    bfill[t] = ex;
    if (t == 255) bstart[NBUCK] = ex + v;  // == N_EDGES
}

// bin edges into bucket regions of temp[]
__global__ __launch_bounds__(256) void k_binfill(const int* __restrict__ src,
                                                 const int* __restrict__ dst,
                                                 int* __restrict__ bfill,
                                                 int2* __restrict__ temp) {
    __shared__ int h[NBUCK], gp[NBUCK], rk[NBUCK];
    int t = threadIdx.x;
    h[t] = 0; rk[t] = 0;
    __syncthreads();
    int base = blockIdx.x * BINBLK;
    int ss[16], dd[16];
    #pragma unroll
    for (int i = 0; i < 16; i++) {
        int e = base + i * 256 + t;
        bool ok = e < N_EDGES;
        ss[i] = ok ? src[e] : 0;
        dd[i] = ok ? dst[e] : -1;
        if (ok) atomicAdd(&h[dd[i] >> BUCK_SHIFT], 1);
    }
    __syncthreads();
    if (h[t]) gp[t] = atomicAdd(&bfill[t], h[t]);
    __syncthreads();
    #pragma unroll
    for (int i = 0; i < 16; i++) {
        if (dd[i] >= 0) {
            int b = dd[i] >> BUCK_SHIFT;
            int r = atomicAdd(&rk[b], 1);
            temp[gp[b] + r] = make_int2(ss[i], dd[i]);
        }
    }
}

// one block per bucket: per-node counts/offsets/dis in LDS, then confined scatter
__global__ __launch_bounds__(256) void k_csrbuild(const int2* __restrict__ temp,
                                                  const int* __restrict__ bstart,
                                                  int* __restrict__ offs,
                                                  float* __restrict__ dis,
                                                  int* __restrict__ csr_src) {
    __shared__ int cnt[256], loff[256], rk[256];
    int b = blockIdx.x, t = threadIdx.x;
    int e0 = bstart[b], e1 = bstart[b + 1];
    int n0 = b << BUCK_SHIFT;
    cnt[t] = 0; rk[t] = 0;
    __syncthreads();
    for (int e = e0 + t; e < e1; e += 256)
        atomicAdd(&cnt[temp[e].y - n0], 1);
    __syncthreads();
    int c = cnt[t];
    int ex = block_excl_scan256(c, t);
    loff[t] = ex;
    int n = n0 + t;
    if (n < N_NODES) {
        offs[n] = e0 + ex;
        dis[n] = rsqrtf((float)c + 1.0f);
    }
    if (b == 0 && t == 0) offs[N_NODES] = N_EDGES;
    __syncthreads();
    for (int e = e0 + t; e < e1; e += 256) {
        int2 v = temp[e];
        int li = v.y - n0;
        int r = atomicAdd(&rk[li], 1);
        csr_src[e0 + loff[li] + r] = v.x;
    }
}

// ---------------- graph counts via binary search on sorted batch ----------------
__global__ void k_gcounts(const int* __restrict__ batch, int* __restrict__ counts) {
    __shared__ int ub[N_GRAPHS];
    int g = threadIdx.x;
    int lo = 0, hi = N_NODES;
    while (lo < hi) {
        int mid = (lo + hi) >> 1;
        if (batch[mid] <= g) lo = mid + 1; else hi = mid;
    }
    ub[g] = lo;
    __syncthreads();
    counts[g] = lo - (g ? ub[g - 1] : 0);
}

// ---------------- layer 1 in 9-dim space ----------------
__global__ void k_pad(const float* __restrict__ x, float* __restrict__ x16) {
    int idx = blockIdx.x * blockDim.x + threadIdx.x;
    if (idx >= N_NODES * 16) return;
    int n = idx >> 4, f = idx & 15;
    x16[idx] = (f < 9) ? x[n * 9 + f] : 0.f;
}

// y[n] = dn * sum_e dis_s*x16[src] + dn^2*x16[n]
__global__ __launch_bounds__(256) void k_agg9(const float* __restrict__ x16,
                                              const int* __restrict__ offs,
                                              const int* __restrict__ csr_src,
                                              const float* __restrict__ dis,
                                              float* __restrict__ y) {
    int wv = threadIdx.x >> 6, lane = threadIdx.x & 63;
    int n = blockIdx.x * 4 + wv;
    if (n >= N_NODES) return;
    int slot = lane >> 4, fl = lane & 15;
    int e0 = offs[n], e1 = offs[n + 1];
    float acc = 0.f;
    for (int e = e0 + slot; e < e1; e += 16) {
        int ss[4]; float cc[4];
        #pragma unroll
        for (int i = 0; i < 4; i++) {
            int ei = e + i * 4;
            bool ok = ei < e1;
            ss[i] = ok ? csr_src[ei] : n;
            cc[i] = ok ? dis[ss[i]] : 0.f;
        }
        #pragma unroll
        for (int i = 0; i < 4; i++)
            acc += cc[i] * x16[(size_t)ss[i] * 16 + fl];
    }
    acc += __shfl_xor(acc, 16, 64);
    acc += __shfl_xor(acc, 32, 64);
    float dn = dis[n];
    acc = dn * acc + dn * dn * x16[(size_t)n * 16 + fl];
    if (slot == 0) y[(size_t)n * 16 + fl] = acc;
}

// ---------------- fused layer1-gemm + relu + layer2-gemm ----------------
// out = bf16( relu(y16 @ W1 + b1) @ W2 ),  y16:[N,16] (9 used)
__global__ __launch_bounds__(256) void k_fused12(const float* __restrict__ y16,
                                                 const float* __restrict__ W1,
                                                 const float* __restrict__ b1,
                                                 const float* __restrict__ W2,
                                                 unsigned* __restrict__ out_bf) {
    __shared__ float htile[64 * 128];
    __shared__ float ytile[64 * 16];
    int t = threadIdx.x;
    int n0 = blockIdx.x * 64;
    // stage y tile (64x16 floats = 256 float4, one per thread)
    ((float4*)ytile)[t] = ((const float4*)(y16 + (size_t)n0 * 16))[t];
    __syncthreads();
    int q = t & 31;    // feature quad j = 4q..4q+3
    int tn = t >> 5;   // rows tn*8..tn*8+7
    // h1 = relu(y @ W1 + b1) for my 8 rows x 4 cols
    const float4* W14 = (const float4*)W1;
    float4 w1q[9];
    #pragma unroll
    for (int k = 0; k < 9; k++) w1q[k] = W14[k * 32 + q];
    float4 bq = ((const float4*)b1)[q];
    #pragma unroll
    for (int r = 0; r < 8; r++) {
        int row = tn * 8 + r;
        float4 a = bq;
        #pragma unroll
        for (int k = 0; k < 9; k++) {
            float yv = ytile[row * 16 + k];
            a.x += yv * w1q[k].x; a.y += yv * w1q[k].y;
            a.z += yv * w1q[k].z; a.w += yv * w1q[k].w;
        }
        *(float4*)&htile[row * 128 + 4 * q] =
            make_float4(fmaxf(a.x, 0.f), fmaxf(a.y, 0.f),
                        fmaxf(a.z, 0.f), fmaxf(a.w, 0.f));
    }
    __syncthreads();
    // h1 @ W2
    float4 acc[8];
    #pragma unroll
    for (int r = 0; r < 8; r++) acc[r] = make_float4(0.f, 0.f, 0.f, 0.f);
    const float4* W4 = (const float4*)W2;
    for (int k = 0; k < 128; k += 2) {
        float4 w0 = W4[k * 32 + q];
        float4 w1 = W4[(k + 1) * 32 + q];
        #pragma unroll
        for (int r = 0; r < 8; r++) {
            int row = tn * 8 + r;
            float2 hk = *(const float2*)&htile[row * 128 + k];
            acc[r].x += hk.x * w0.x; acc[r].y += hk.x * w0.y;
            acc[r].z += hk.x * w0.z; acc[r].w += hk.x * w0.w;
            acc[r].x += hk.y * w1.x; acc[r].y += hk.y * w1.y;
            acc[r].z += hk.y * w1.z; acc[r].w += hk.y * w1.w;
        }
    }
    uint2* out8 = (uint2*)out_bf;
    #pragma unroll
    for (int r = 0; r < 8; r++) {
        int n = n0 + tn * 8 + r;
        if (n < N_NODES) out8[(size_t)n * 32 + q] = f4_to_bf4(acc[r]);
    }
}

// ---------------- bf16 gather-agg ----------------
// wave-per-node: lane = 4 bf16 (8B), 32 lanes/row, 2 edges per load slot,
// 16 edges in flight; coef gathered from L2-resident dis
template <int RELU, int HAS_BIAS>
__global__ __launch_bounds__(256) void k_agg_t(const uint2* __restrict__ h8,
                                               const int* __restrict__ offs,
                                               const int* __restrict__ csr_src,
                                               const float* __restrict__ dis,
                                               const float* __restrict__ bias,
                                               uint2* __restrict__ out) {
    int wv = threadIdx.x >> 6, lane = threadIdx.x & 63;
    int n = blockIdx.x * 4 + wv;
    if (n >= N_NODES) return;
    int half = lane >> 5;
    int fl = lane & 31;
    int e0 = offs[n], e1 = offs[n + 1];
    float4 acc = make_float4(0.f, 0.f, 0.f, 0.f);
    for (int e = e0 + half; e < e1; e += 16) {
        int ss[8]; float cc[8];
        #pragma unroll
        for (int i = 0; i < 8; i++) {
            int ei = e + i * 2;
            bool ok = ei < e1;
            ss[i] = ok ? csr_src[ei] : n;
            cc[i] = ok ? dis[ss[i]] : 0.f;
        }
        uint2 rows[8];
        #pragma unroll
        for (int i = 0; i < 8; i++)
            rows[i] = h8[(size_t)ss[i] * 32 + fl];
        #pragma unroll
        for (int i = 0; i < 8; i++) {
            float4 r = bf4_to_f4(rows[i]);
            acc.x += cc[i] * r.x;
            acc.y += cc[i] * r.y;
            acc.z += cc[i] * r.z;
            acc.w += cc[i] * r.w;
        }
    }
    acc.x += __shfl_xor(acc.x, 32, 64);
    acc.y += __shfl_xor(acc.y, 32, 64);
    acc.z += __shfl_xor(acc.z, 32, 64);
    acc.w += __shfl_xor(acc.w, 32, 64);
    float dn = dis[n];
    float4 hv = bf4_to_f4(h8[(size_t)n * 32 + fl]);
    acc.x = dn * acc.x + dn * dn * hv.x;
    acc.y = dn * acc.y + dn * dn * hv.y;
    acc.z = dn * acc.z + dn * dn * hv.z;
    acc.w = dn * acc.w + dn * dn * hv.w;
    if (HAS_BIAS) {
        float4 bb = ((const float4*)bias)[fl];
        acc.x += bb.x; acc.y += bb.y; acc.z += bb.z; acc.w += bb.w;
    }
    if (RELU) {
        acc.x = fmaxf(acc.x, 0.f);
        acc.y = fmaxf(acc.y, 0.f);
        acc.z = fmaxf(acc.z, 0.f);
        acc.w = fmaxf(acc.w, 0.f);
    }
    if (half == 0) out[(size_t)n * 32 + fl] = f4_to_bf4(acc);
}

// ---------------- pooling (bf16 input, fp32 atomic accumulate) ----------------
__global__ void k_poolb(const unsigned* __restrict__ Xb, const int* __restrict__ batch,
                        float* __restrict__ sums) {
    int u = threadIdx.x;  // 0..63, features 2u,2u+1
    int n0 = blockIdx.x * 16;
    int gprev = -1;
    float a0 = 0.f, a1 = 0.f;
    for (int i = 0; i < 16; i++) {
        int n = n0 + i;
        if (n >= N_NODES) break;
        int g = batch[n];
        unsigned v = Xb[(size_t)n * 64 + u];
        if (g != gprev) {
            if (gprev >= 0) {
                atomicAdd(&sums[gprev * 128 + 2 * u], a0);
                atomicAdd(&sums[gprev * 128 + 2 * u + 1], a1);
            }
            a0 = a1 = 0.f;
            gprev = g;
        }
        a0 += __uint_as_float(v << 16);
        a1 += __uint_as_float(v & 0xffff0000u);
    }
    if (gprev >= 0) {
        atomicAdd(&sums[gprev * 128 + 2 * u], a0);
        atomicAdd(&sums[gprev * 128 + 2 * u + 1], a1);
    }
}

__global__ void k_final(const float* __restrict__ sums, const int* __restrict__ counts,
                        const float* __restrict__ W3, const float* __restrict__ b3,
                        float* __restrict__ out) {
    int idx = blockIdx.x * blockDim.x + threadIdx.x;
    if (idx >= N_GRAPHS * HID) return;
    int g = idx >> 7, j = idx & 127;
    float inv = 1.0f / fmaxf((float)counts[g], 1.0f);
    const float* srow = sums + g * 128;
    float acc = 0.f;
    for (int k = 0; k < 128; k++) acc += srow[k] * W3[k * 128 + j];
    out[idx] = acc * inv + b3[j];
}

extern "C" void kernel_launch(void* const* d_in, const int* in_sizes, int n_in,
                              void* d_out, int out_size, void* d_ws, size_t ws_size,
                              hipStream_t stream) {
    const float* x     = (const float*)d_in[0];
    const int*   ei    = (const int*)d_in[1];
    const int*   batch = (const int*)d_in[2];
    const float* W1    = (const float*)d_in[3];
    const float* b1    = (const float*)d_in[4];
    const float* W2    = (const float*)d_in[5];
    const float* b2    = (const float*)d_in[6];
    const float* W3    = (const float*)d_in[7];
    const float* b3    = (const float*)d_in[8];
    float* out = (float*)d_out;
    const int* src = ei;
    const int* dst = ei + N_EDGES;

    char* ws = (char*)d_ws;
    size_t off = 0;
    auto alloc = [&](size_t bytes) -> void* {
        void* p = ws + off;
        off += (bytes + 255) & ~(size_t)255;
        return p;
    };
    unsigned* hb1     = (unsigned*)alloc((size_t)N_NODES * 64 * 4);  // bf16 [N,128]
    unsigned* hb2     = (unsigned*)alloc((size_t)N_NODES * 64 * 4);  // bf16 [N,128]
    int2*     temp    = (int2*)alloc((size_t)N_EDGES * 8);           // binned (src,dst)
    int*      csr_src = (int*)alloc((size_t)N_EDGES * 4);
    int*      bhist   = (int*)alloc((size_t)NBUCK * 4);
    int*      bstart  = (int*)alloc((size_t)(NBUCK + 1) * 4);
    int*      bfill   = (int*)alloc((size_t)NBUCK * 4);
    int*      offs    = (int*)alloc((size_t)(N_NODES + 1) * 4);
    float*    dis     = (float*)alloc((size_t)N_NODES * 4);
    float*    sums    = (float*)alloc((size_t)N_GRAPHS * 128 * 4);
    int*      counts  = (int*)alloc((size_t)N_GRAPHS * 4);
    float*    x16     = (float*)alloc((size_t)N_NODES * 16 * 4);
    float*    y16     = (float*)alloc((size_t)(N_NODES + 64) * 16 * 4);  // +pad for tile overread

    hipMemsetAsync(bhist, 0, (size_t)NBUCK * 4, stream);
    hipMemsetAsync(sums, 0, (size_t)N_GRAPHS * 128 * 4, stream);

    const int binGrid = (N_EDGES + BINBLK - 1) / BINBLK;  // 391
    k_bhist<<<binGrid, 256, 0, stream>>>(dst, bhist);
    k_bscan<<<1, 256, 0, stream>>>(bhist, bstart, bfill);
    k_binfill<<<binGrid, 256, 0, stream>>>(src, dst, bfill, temp);
    k_csrbuild<<<NBUCK_USED, 256, 0, stream>>>(temp, bstart, offs, dis, csr_src);
    k_gcounts<<<1, N_GRAPHS, 0, stream>>>(batch, counts);
    k_pad<<<(N_NODES * 16 + 255) / 256, 256, 0, stream>>>(x, x16);

    // layer 1 aggregate in 9-dim space
    k_agg9<<<(N_NODES + 3) / 4, 256, 0, stream>>>(x16, offs, csr_src, dis, y16);
    // fused: hb1 = bf16( relu(y@W1+b1) @ W2 )
    k_fused12<<<(N_NODES + 63) / 64, 256, 0, stream>>>(y16, W1, b1, W2, hb1);
    // layer 2 agg: hb2 = bf16(relu(agg(hb1) + b2))
    k_agg_t<1, 1><<<(N_NODES + 3) / 4, 256, 0, stream>>>((const uint2*)hb1, offs,
                                                         csr_src, dis, b2, (uint2*)hb2);
    // layer 3 agg (W3 deferred past pooling): Xb = bf16(agg(hb2)), reuse hb1
    k_agg_t<0, 0><<<(N_NODES + 3) / 4, 256, 0, stream>>>((const uint2*)hb2, offs,
                                                         csr_src, dis, nullptr, (uint2*)hb1);
    // pool + final tiny GEMM
    k_poolb<<<(N_NODES + 15) / 16, 64, 0, stream>>>(hb1, batch, sums);
    k_final<<<(N_GRAPHS * HID + 255) / 256, 256, 0, stream>>>(sums, counts, W3, b3, out);
}